// Round 8
// baseline (195.943 us; speedup 1.0000x reference)
//
#include <hip/hip_runtime.h>
#include <hip/hip_bf16.h>
#include <cstdint>
#include <cstddef>

typedef unsigned short u16;
typedef unsigned int u32;
using bf16x8 = __attribute__((ext_vector_type(8))) __bf16;
using f32x4  = __attribute__((ext_vector_type(4))) float;

#define N_EMBD 1024
#define N_HEAD 16
#define HEAD_DIM 64
#define BATCH 2
#define SEQ 2048
#define M_TOT (BATCH * SEQ)  // 4096
#define NEG_BIG (-3.0e38f)

// ---------- helpers ----------

__device__ __forceinline__ u16 f2bf(float f) {
  union { float f; u32 u; } v;
  v.f = f;
  u32 u = v.u;
  u32 r = (u + 0x7FFFu + ((u >> 16) & 1u)) >> 16;  // RNE
  return (u16)r;
}

__device__ __forceinline__ float bf2f(u16 h) {
  union { u32 u; float f; } v;
  v.u = ((u32)h) << 16;
  return v.f;
}

__device__ __forceinline__ u32 packbf2(float a, float b) {
  union { __hip_bfloat162 h; u32 u; } cv;
  cv.h = __float22bfloat162_rn(float2{a, b});
  return cv.u;
}

// async global->LDS, 16B per lane; dst is wave-uniform base (HW adds lane*16)
__device__ __forceinline__ void g2l16(const void* g, void* l) {
  __builtin_amdgcn_global_load_lds((__attribute__((address_space(1))) void*)(g),
                                   (__attribute__((address_space(3))) void*)(l),
                                   16, 0, 0);
}

// Pipelined barriers: wait only the oldest in-flight loads, keep the newest
// N (next tile's prefetch) in flight across the barrier.
__device__ __forceinline__ void pipe_barrier4() {
  asm volatile("s_waitcnt vmcnt(4)\n\ts_barrier" ::: "memory");
}
__device__ __forceinline__ void pipe_barrier3() {
  asm volatile("s_waitcnt vmcnt(3)\n\ts_barrier" ::: "memory");
}
__device__ __forceinline__ void pipe_barrier0() {
  asm volatile("s_waitcnt vmcnt(0)\n\ts_barrier" ::: "memory");
}
__device__ __forceinline__ void ds_barrier() {
  asm volatile("s_waitcnt lgkmcnt(0)\n\ts_barrier" ::: "memory");
}

// ---------- fused prep: x fp32->bf16 + both weight transposes ----------
// blocks [0,2048): conv; [2048,2816): w_attn^T (48x16); [2816,3072): w_proj^T.

__global__ __launch_bounds__(256) void prep_kernel(const float* __restrict__ x,
                                                   u16* __restrict__ xb,
                                                   const float* __restrict__ wa,
                                                   u16* __restrict__ waT,
                                                   const float* __restrict__ wp,
                                                   u16* __restrict__ wpT) {
  __shared__ float tile[64][65];
  const int bid = blockIdx.x;
  const int tid = threadIdx.x;
  if (bid < 2048) {
    int i = (bid * 256 + tid) * 8;
    float4 a = *(const float4*)(x + i);
    float4 b = *(const float4*)(x + i + 4);
    union { u16 s[8]; uint4 v; } o;
    o.s[0] = f2bf(a.x); o.s[1] = f2bf(a.y); o.s[2] = f2bf(a.z); o.s[3] = f2bf(a.w);
    o.s[4] = f2bf(b.x); o.s[5] = f2bf(b.y); o.s[6] = f2bf(b.z); o.s[7] = f2bf(b.w);
    *(uint4*)(xb + i) = o.v;
    return;
  }
  const float* src; u16* dst; int R, C, c0, r0;
  if (bid < 2048 + 768) {
    int t = bid - 2048;
    src = wa; dst = waT; R = N_EMBD; C = 3 * N_EMBD;
    c0 = (t % 48) * 64; r0 = (t / 48) * 64;
  } else {
    int t = bid - 2816;
    src = wp; dst = wpT; R = N_EMBD; C = N_EMBD;
    c0 = (t % 16) * 64; r0 = (t / 16) * 64;
  }
#pragma unroll
  for (int i = 0; i < 16; ++i) {
    int idx = tid + i * 256;
    int r = idx >> 6, c = idx & 63;
    tile[r][c] = src[(size_t)(r0 + r) * C + (c0 + c)];
  }
  __syncthreads();
#pragma unroll
  for (int i = 0; i < 16; ++i) {
    int idx = tid + i * 256;
    int cc = idx >> 6, rr = idx & 63;
    dst[(size_t)(c0 + cc) * R + (r0 + rr)] = f2bf(tile[rr][cc]);
  }
}

// ---------- GEMM: C[M,TN-tiles] = A[M,K] * Bt[N,K]^T + bias ----------
// NBUF=3, prefetch distance 2, one raw s_barrier/iter, vmcnt keeps the next
// tile's loads in flight. TN = 128 (4 waves 2x2 of 64x64) or 64 (4 waves of
// 32x64 -> 512 blocks for GEMM2's small N).
// MODE 0: fp32 out row-major [M,N]
// MODE 1: qkv epilogue -> q[B,H,S,D], k[B,H,S,D], v^T[B,H,D,S], all bf16

template <int MODE, int TN>
__global__ __launch_bounds__(256) void gemm_bt(const u16* __restrict__ A,
                                               const u16* __restrict__ Bt,
                                               const float* __restrict__ bias,
                                               float* __restrict__ outF,
                                               u16* __restrict__ qb, u16* __restrict__ kb,
                                               u16* __restrict__ vtb, int M, int N, int K) {
  constexpr int MI = (TN == 128) ? 4 : 2;   // m-frags per wave
  __shared__ u16 As[3][128 * 32];
  __shared__ u16 Bs[3][TN * 32];
  const int tid = threadIdx.x;
  const int wid = tid >> 6;
  const int lane = tid & 63;
  const int quad = lane >> 4;
  const int l15 = lane & 15;
  const int m0 = blockIdx.y * 128;
  const int n0 = blockIdx.x * TN;
  const int wm = (TN == 128) ? (wid >> 1) : wid;
  const int wn = (TN == 128) ? (wid & 1) : 0;

  f32x4 acc[MI][4];
#pragma unroll
  for (int i = 0; i < MI; ++i)
#pragma unroll
    for (int j = 0; j < 4; ++j) acc[i][j] = (f32x4){0.f, 0.f, 0.f, 0.f};

  const int lrow = lane >> 2;          // 0..15
  const int lchunk = (lane & 3) * 8;   // element offset within 32-col row

  auto stage = [&](int t, int b) {
#pragma unroll
    for (int i = 0; i < 2; ++i) {
      int li = wid * 2 + i;
      g2l16(A + (size_t)(m0 + li * 16 + lrow) * K + t * 32 + lchunk, &As[b][li * 512]);
    }
    if (TN == 128) {
#pragma unroll
      for (int i = 0; i < 2; ++i) {
        int li = wid * 2 + i;
        g2l16(Bt + (size_t)(n0 + li * 16 + lrow) * K + t * 32 + lchunk, &Bs[b][li * 512]);
      }
    } else {
      g2l16(Bt + (size_t)(n0 + wid * 16 + lrow) * K + t * 32 + lchunk, &Bs[b][wid * 512]);
    }
  };

  const int niter = K >> 5;
  stage(0, 0);
  stage(1, 1);

  int buf = 0;
  for (int it = 0; it < niter; ++it) {
    if (it < niter - 1) {
      if (TN == 128) pipe_barrier4(); else pipe_barrier3();
    } else {
      pipe_barrier0();
    }
    if (it + 2 < niter) {
      int b2 = buf + 2; if (b2 >= 3) b2 -= 3;
      stage(it + 2, b2);
    }
    bf16x8 af[MI], bfv[4];
#pragma unroll
    for (int i = 0; i < MI; ++i)
      af[i] = *(const bf16x8*)&As[buf][(wm * (MI * 16) + i * 16 + l15) * 32 + quad * 8];
#pragma unroll
    for (int j = 0; j < 4; ++j)
      bfv[j] = *(const bf16x8*)&Bs[buf][(wn * 64 + j * 16 + l15) * 32 + quad * 8];
#pragma unroll
    for (int i = 0; i < MI; ++i)
#pragma unroll
      for (int j = 0; j < 4; ++j)
        acc[i][j] = __builtin_amdgcn_mfma_f32_16x16x32_bf16(af[i], bfv[j], acc[i][j], 0, 0, 0);
    buf = (buf + 1 == 3) ? 0 : buf + 1;
  }

  float bj[4];
#pragma unroll
  for (int j = 0; j < 4; ++j) bj[j] = bias[n0 + wn * 64 + j * 16 + l15];

  if (MODE == 1 && (n0 >> 10) == 2) {
    // v slab: pack 4 consecutive s into one 8B store; vtb[bh][d][s]
#pragma unroll
    for (int i = 0; i < MI; ++i) {
#pragma unroll
      for (int j = 0; j < 4; ++j) {
        int col = n0 + wn * 64 + j * 16 + l15;
        int e = col & 1023;
        int h = e >> 6, d = e & 63;
        int mg0 = m0 + wm * (MI * 16) + i * 16 + quad * 4;
        int b = mg0 >> 11, s0 = mg0 & 2047;
        int bh = b * N_HEAD + h;
        uint2 pk;
        pk.x = packbf2(acc[i][j][0] + bj[j], acc[i][j][1] + bj[j]);
        pk.y = packbf2(acc[i][j][2] + bj[j], acc[i][j][3] + bj[j]);
        *(uint2*)&vtb[((size_t)bh * HEAD_DIM + d) * SEQ + s0] = pk;
      }
    }
    return;
  }

#pragma unroll
  for (int i = 0; i < MI; ++i) {
#pragma unroll
    for (int j = 0; j < 4; ++j) {
      int col = n0 + wn * 64 + j * 16 + l15;
#pragma unroll
      for (int r = 0; r < 4; ++r) {
        int m_g = m0 + wm * (MI * 16) + i * 16 + quad * 4 + r;
        float v = acc[i][j][r] + bj[j];
        if (MODE == 0) {
          outF[(size_t)m_g * N + col] = v;
        } else {
          int which = col >> 10;      // 0=q 1=k (v handled above)
          int e = col & 1023;
          int h = e >> 6, d = e & 63;
          int b = m_g >> 11, s = m_g & 2047;
          int bh = b * N_HEAD + h;
          u16 bv = f2bf(v);
          if (which == 0)
            qb[((size_t)bh * SEQ + s) * HEAD_DIM + d] = bv;
          else
            kb[((size_t)bh * SEQ + s) * HEAD_DIM + d] = bv;
        }
      }
    }
  }
}

// ---------- split-K flash attention (causal) ----------
// Q-block 128 (wave owns 32 q rows = 2 frags). Key range of q-tile qb
// (2qb+2 tiles) split into two halves of qb+1 tiles; grid (32, 32 bh).
// K NBUF=2, V NBUF=2; V frags read to regs BEFORE the ds_barrier (round-5
// ordering, measured 84 VGPRs -> no spills) so stage(j+2) can reuse both
// buffers right after the barrier. Ps uses stride 64 with a 16B-chunk XOR
// swizzle (phys16 = c16 ^ (l15&7)): write uint2 and read b128 are both
// 2 lanes/bank = free, and LDS drops to 16K+16K+8K = 40960 B exactly ->
// 4 blocks/CU (16 waves/CU). One vm-barrier (vmcnt(4)) + one ds-barrier
// per iter. Partials: unnormalized O^T bf16 + (m,l); merged by attn_merge.

__global__ __launch_bounds__(256, 3) void attn_split(const u16* __restrict__ q,
                                                     const u16* __restrict__ k,
                                                     const u16* __restrict__ vt,
                                                     u16* __restrict__ po,
                                                     float2* __restrict__ ml) {
  __shared__ u16 Ks[2][64 * 64];
  __shared__ u16 Vs[2][64 * 64];   // [d][key]
  __shared__ u16 Ps[4][16 * 64];   // per-wave P [q][key], 16B-chunk XOR swizzle

  const int tid = threadIdx.x;
  const int wid = tid >> 6;
  const int lane = tid & 63;
  const int quad = lane >> 4;
  const int l15 = lane & 15;
  const int l7 = l15 & 7;
  const int raw = blockIdx.x;
  const int half = raw & 1;
  const int cc = raw >> 1;
  const int yy = blockIdx.y;
  const int g = (cc + yy) & 7;
  const int hi = ((cc >> 3) ^ (yy >> 3)) & 1;
  const int qb = hi ? (15 - g) : g;
  const size_t base = (size_t)yy * SEQ * HEAD_DIM;
  const int lrow8 = lane >> 3;                 // 0..7
  const int swz8 = ((lane & 7) ^ lrow8) * 8;   // swizzled source chunk
  const int ni = qb + 1;                       // tiles in this half
  const int t0 = half * ni;                    // first global tile index
  const int p = (yy * 16 + qb) * 2 + half;     // partial slot

  // Q B-frags, direct to regs (4 b128 global loads; oldest in vmcnt order)
  bf16x8 bq[2][2];
#pragma unroll
  for (int qf = 0; qf < 2; ++qf)
#pragma unroll
    for (int kk = 0; kk < 2; ++kk)
      bq[qf][kk] = *(const bf16x8*)(q + base +
          (size_t)(qb * 128 + wid * 32 + qf * 16 + l15) * HEAD_DIM + kk * 32 + quad * 8);

  auto stageK = [&](int j, int b) {
#pragma unroll
    for (int i = 0; i < 2; ++i) {
      int li = wid * 2 + i;
      g2l16(k + base + (size_t)(j * 64 + li * 8 + lrow8) * HEAD_DIM + swz8, &Ks[b][li * 512]);
    }
  };
  auto stageV = [&](int j, int b) {
#pragma unroll
    for (int i = 0; i < 2; ++i) {
      int li = wid * 2 + i;
      g2l16(vt + base + (size_t)(li * 8 + lrow8) * SEQ + j * 64 + swz8, &Vs[b][li * 512]);
    }
  };

  stageK(t0, 0);
  stageV(t0, 0);
  if (ni >= 2) { stageK(t0 + 1, 1); stageV(t0 + 1, 1); }

  float m2[2] = {NEG_BIG, NEG_BIG}, l2[2] = {0.f, 0.f};
  f32x4 o[2][4];
#pragma unroll
  for (int qf = 0; qf < 2; ++qf)
#pragma unroll
    for (int u = 0; u < 4; ++u) o[qf][u] = (f32x4){0.f, 0.f, 0.f, 0.f};

  const float c2 = 0.125f * 1.44269504f;  // (1/sqrt(64)) * log2(e)
  const int mask_from = 2 * qb;

  for (int i = 0; i < ni; ++i) {
    const int jj = t0 + i;
    const int buf = i & 1;
    // outstanding here: tile jj+1's K+V (4 loads) -> vmcnt(4) proves jj landed
    if (i < ni - 1) pipe_barrier4(); else pipe_barrier0();

    // V frags to regs first (used only after softmax; read must precede the
    // ds_barrier because stage(jj+2) reuses this buffer)
    bf16x8 vv[4][2];
#pragma unroll
    for (int u = 0; u < 4; ++u)
#pragma unroll
      for (int kk = 0; kk < 2; ++kk)
        vv[u][kk] = *(const bf16x8*)&Vs[buf][(u * 16 + l15) * 64 + (((kk * 4 + quad) ^ l7) * 8)];

    // S^T = K · Q^T : K frag read once, feeds both q-frags
    f32x4 st[2][4];
#pragma unroll
    for (int qf = 0; qf < 2; ++qf)
#pragma unroll
      for (int t = 0; t < 4; ++t) st[qf][t] = (f32x4){0.f, 0.f, 0.f, 0.f};
#pragma unroll
    for (int kk = 0; kk < 2; ++kk)
#pragma unroll
      for (int t = 0; t < 4; ++t) {
        bf16x8 ka = *(const bf16x8*)&Ks[buf][(t * 16 + l15) * 64 + (((kk * 4 + quad) ^ l7) * 8)];
        st[0][t] = __builtin_amdgcn_mfma_f32_16x16x32_bf16(ka, bq[0][kk], st[0][t], 0, 0, 0);
        st[1][t] = __builtin_amdgcn_mfma_f32_16x16x32_bf16(ka, bq[1][kk], st[1][t], 0, 0, 0);
      }

    // all waves' K/V reads of this buffer retired -> reusable
    ds_barrier();
    if (i + 2 < ni) { stageK(jj + 2, buf); stageV(jj + 2, buf); }

    // causal mask (global tile index vs q rows)
    if (jj >= mask_from) {
#pragma unroll
      for (int qf = 0; qf < 2; ++qf) {
        int qrow = qb * 128 + wid * 32 + qf * 16 + l15;
#pragma unroll
        for (int t = 0; t < 4; ++t)
#pragma unroll
          for (int r = 0; r < 4; ++r) {
            int key = jj * 64 + t * 16 + quad * 4 + r;
            if (key > qrow) st[qf][t][r] = -INFINITY;
          }
      }
    }

    // online softmax (log2 domain), per q-frag; raw v_exp_f32
#pragma unroll
    for (int qf = 0; qf < 2; ++qf) {
      float mx = -INFINITY;
#pragma unroll
      for (int t = 0; t < 4; ++t)
#pragma unroll
        for (int r = 0; r < 4; ++r) mx = fmaxf(mx, st[qf][t][r]);
      mx = fmaxf(mx, __shfl_xor(mx, 16));
      mx = fmaxf(mx, __shfl_xor(mx, 32));
      float m2new = fmaxf(m2[qf], mx * c2);
      float s = 0.f;
#pragma unroll
      for (int t = 0; t < 4; ++t)
#pragma unroll
        for (int r = 0; r < 4; ++r) {
          float pv = __builtin_amdgcn_exp2f(__builtin_fmaf(st[qf][t][r], c2, -m2new));
          st[qf][t][r] = pv;
          s += pv;
        }
      s += __shfl_xor(s, 16);
      s += __shfl_xor(s, 32);
      if (__any(m2new > m2[qf])) {
        float al = __builtin_amdgcn_exp2f(m2[qf] - m2new);
        l2[qf] = l2[qf] * al + s;
#pragma unroll
        for (int u = 0; u < 4; ++u)
#pragma unroll
          for (int r = 0; r < 4; ++r) o[qf][u][r] *= al;
      } else {
        l2[qf] += s;
      }
      m2[qf] = m2new;
    }

    // per q-frag: P staging (wave-private, swizzled) then O^T += V^T · P^T
#pragma unroll
    for (int qf = 0; qf < 2; ++qf) {
#pragma unroll
      for (int t = 0; t < 4; ++t) {
        uint2 pk;
        pk.x = packbf2(st[qf][t][0], st[qf][t][1]);
        pk.y = packbf2(st[qf][t][2], st[qf][t][3]);
        // logical 16B chunk c16 = 2t + (quad>>1), low half sel = quad&1
        *(uint2*)&Ps[wid][l15 * 64 + (((2 * t + (quad >> 1)) ^ l7) * 8) + (quad & 1) * 4] = pk;
      }
#pragma unroll
      for (int kk = 0; kk < 2; ++kk) {
        // logical 16B chunk c16 = 4kk + quad
        bf16x8 bp = *(const bf16x8*)&Ps[wid][l15 * 64 + (((4 * kk + quad) ^ l7) * 8)];
#pragma unroll
        for (int u = 0; u < 4; ++u)
          o[qf][u] = __builtin_amdgcn_mfma_f32_16x16x32_bf16(vv[u][kk], bp, o[qf][u], 0, 0, 0);
      }
    }
  }

  // epilogue: unnormalized O^T partial (bf16) + (m,l) per q row
#pragma unroll
  for (int qf = 0; qf < 2; ++qf) {
    const int qloc = wid * 32 + qf * 16 + l15;
    u16* pr = po + (size_t)p * (128 * 64) + (size_t)qloc * 64;
#pragma unroll
    for (int u = 0; u < 4; ++u) {
      uint2 pk;
      pk.x = packbf2(o[qf][u][0], o[qf][u][1]);
      pk.y = packbf2(o[qf][u][2], o[qf][u][3]);
      *(uint2*)&pr[u * 16 + quad * 4] = pk;
    }
    if (quad == 0) ml[(size_t)p * 128 + qloc] = float2{m2[qf], l2[qf]};
  }
}

// ---------- merge two split-K partials -> ctx ----------
// grid (16 qb, 32 bh) x 256 thr; thread owns q = tid>>1, d = (tid&1)*32..+31.

__global__ __launch_bounds__(256) void attn_merge(const u16* __restrict__ po,
                                                  const float2* __restrict__ ml,
                                                  u16* __restrict__ ctx) {
  const int qb = blockIdx.x, yy = blockIdx.y;
  const int tid = threadIdx.x;
  const int qloc = tid >> 1;
  const int d0 = (tid & 1) * 32;
  const int p0 = (yy * 16 + qb) * 2;
  const float2 a = ml[(size_t)p0 * 128 + qloc];
  const float2 b = ml[(size_t)(p0 + 1) * 128 + qloc];
  const float m = fmaxf(a.x, b.x);
  const float wA = __builtin_amdgcn_exp2f(a.x - m);
  const float wB = __builtin_amdgcn_exp2f(b.x - m);
  const float li = a.y * wA + b.y * wB;
  const float sA = wA / li, sB = wB / li;
  const u16* pa = po + (size_t)p0 * (128 * 64) + (size_t)qloc * 64 + d0;
  const u16* pb = pa + 128 * 64;
  const int bb = yy >> 4, h = yy & 15;
  u16* outp = ctx + ((size_t)(bb * SEQ + qb * 128 + qloc)) * N_EMBD + h * HEAD_DIM + d0;
#pragma unroll
  for (int c = 0; c < 4; ++c) {
    union { uint4 v; u16 s[8]; } ua, ub, uo;
    ua.v = *(const uint4*)(pa + c * 8);
    ub.v = *(const uint4*)(pb + c * 8);
#pragma unroll
    for (int e = 0; e < 8; e += 2) {
      float r0 = bf2f(ua.s[e]) * sA + bf2f(ub.s[e]) * sB;
      float r1 = bf2f(ua.s[e + 1]) * sA + bf2f(ub.s[e + 1]) * sB;
      *(u32*)&uo.s[e] = packbf2(r0, r1);
    }
    *(uint4*)(outp + c * 8) = uo.v;
  }
}

// ---------- fused fallback attention (round-5 structure) ----------

__global__ __launch_bounds__(256, 3) void attn_fused(const u16* __restrict__ q,
                                                     const u16* __restrict__ k,
                                                     const u16* __restrict__ vt,
                                                     u16* __restrict__ ctx) {
  __shared__ u16 Ks[2][64 * 64];
  __shared__ u16 Vs[2][64 * 64];
  __shared__ u16 Ps[4][16 * 72];
  const int tid = threadIdx.x;
  const int wid = tid >> 6;
  const int lane = tid & 63;
  const int quad = lane >> 4;
  const int l15 = lane & 15;
  const int l7 = l15 & 7;
  const int yy = blockIdx.y;
  const int cc = (blockIdx.x + yy) & 15;
  const int qb = (yy < 16) ? cc : 15 - cc;
  const size_t base = (size_t)yy * SEQ * HEAD_DIM;
  const int lrow8 = lane >> 3;
  const int swz8 = ((lane & 7) ^ lrow8) * 8;
  const int nt = 2 * qb + 2;

  bf16x8 bq[2][2];
#pragma unroll
  for (int qf = 0; qf < 2; ++qf)
#pragma unroll
    for (int kk = 0; kk < 2; ++kk)
      bq[qf][kk] = *(const bf16x8*)(q + base +
          (size_t)(qb * 128 + wid * 32 + qf * 16 + l15) * HEAD_DIM + kk * 32 + quad * 8);

  auto stage = [&](int j, int b) {
#pragma unroll
    for (int i = 0; i < 2; ++i) {
      int li = wid * 2 + i;
      int r = li * 8 + lrow8;
      g2l16(k + base + (size_t)(j * 64 + r) * HEAD_DIM + swz8, &Ks[b][li * 512]);
      g2l16(vt + base + (size_t)r * SEQ + j * 64 + swz8, &Vs[b][li * 512]);
    }
  };
  stage(0, 0);
  stage(1, 1);

  float m2[2] = {NEG_BIG, NEG_BIG}, l2[2] = {0.f, 0.f};
  f32x4 o[2][4];
#pragma unroll
  for (int qf = 0; qf < 2; ++qf)
#pragma unroll
    for (int u = 0; u < 4; ++u) o[qf][u] = (f32x4){0.f, 0.f, 0.f, 0.f};
  const float c2 = 0.125f * 1.44269504f;

  int buf = 0;
  for (int j = 0; j < nt; ++j) {
    if (j < nt - 1) pipe_barrier4(); else pipe_barrier0();
    bf16x8 vv[4][2];
#pragma unroll
    for (int u = 0; u < 4; ++u)
#pragma unroll
      for (int kk = 0; kk < 2; ++kk)
        vv[u][kk] = *(const bf16x8*)&Vs[buf][(u * 16 + l15) * 64 + (((kk * 4 + quad) ^ l7) * 8)];
    f32x4 st[2][4];
#pragma unroll
    for (int qf = 0; qf < 2; ++qf)
#pragma unroll
      for (int t = 0; t < 4; ++t) st[qf][t] = (f32x4){0.f, 0.f, 0.f, 0.f};
#pragma unroll
    for (int kk = 0; kk < 2; ++kk)
#pragma unroll
      for (int t = 0; t < 4; ++t) {
        bf16x8 ka = *(const bf16x8*)&Ks[buf][(t * 16 + l15) * 64 + (((kk * 4 + quad) ^ l7) * 8)];
        st[0][t] = __builtin_amdgcn_mfma_f32_16x16x32_bf16(ka, bq[0][kk], st[0][t], 0, 0, 0);
        st[1][t] = __builtin_amdgcn_mfma_f32_16x16x32_bf16(ka, bq[1][kk], st[1][t], 0, 0, 0);
      }
    ds_barrier();
    if (j + 2 < nt) stage(j + 2, buf);
    if (j >= 2 * qb) {
#pragma unroll
      for (int qf = 0; qf < 2; ++qf) {
        int qrow = qb * 128 + wid * 32 + qf * 16 + l15;
#pragma unroll
        for (int t = 0; t < 4; ++t)
#pragma unroll
          for (int r = 0; r < 4; ++r) {
            int key = j * 64 + t * 16 + quad * 4 + r;
            if (key > qrow) st[qf][t][r] = -INFINITY;
          }
      }
    }
#pragma unroll
    for (int qf = 0; qf < 2; ++qf) {
      float mx = -INFINITY;
#pragma unroll
      for (int t = 0; t < 4; ++t)
#pragma unroll
        for (int r = 0; r < 4; ++r) mx = fmaxf(mx, st[qf][t][r]);
      mx = fmaxf(mx, __shfl_xor(mx, 16));
      mx = fmaxf(mx, __shfl_xor(mx, 32));
      float m2new = fmaxf(m2[qf], mx * c2);
      float s = 0.f;
#pragma unroll
      for (int t = 0; t < 4; ++t)
#pragma unroll
        for (int r = 0; r < 4; ++r) {
          float pv = __builtin_amdgcn_exp2f(__builtin_fmaf(st[qf][t][r], c2, -m2new));
          st[qf][t][r] = pv;
          s += pv;
        }
      s += __shfl_xor(s, 16);
      s += __shfl_xor(s, 32);
      if (__any(m2new > m2[qf])) {
        float al = __builtin_amdgcn_exp2f(m2[qf] - m2new);
        l2[qf] = l2[qf] * al + s;
#pragma unroll
        for (int u = 0; u < 4; ++u)
#pragma unroll
          for (int r = 0; r < 4; ++r) o[qf][u][r] *= al;
      } else {
        l2[qf] += s;
      }
      m2[qf] = m2new;
    }
#pragma unroll
    for (int qf = 0; qf < 2; ++qf) {
#pragma unroll
      for (int t = 0; t < 4; ++t) {
        uint2 pk;
        pk.x = packbf2(st[qf][t][0], st[qf][t][1]);
        pk.y = packbf2(st[qf][t][2], st[qf][t][3]);
        *(uint2*)&Ps[wid][l15 * 72 + t * 16 + quad * 4] = pk;
      }
#pragma unroll
      for (int kk = 0; kk < 2; ++kk) {
        bf16x8 bp = *(const bf16x8*)&Ps[wid][l15 * 72 + kk * 32 + quad * 8];
#pragma unroll
        for (int u = 0; u < 4; ++u)
          o[qf][u] = __builtin_amdgcn_mfma_f32_16x16x32_bf16(vv[u][kk], bp, o[qf][u], 0, 0, 0);
      }
    }
    buf ^= 1;
  }
  const int b = yy >> 4, h = yy & 15;
#pragma unroll
  for (int qf = 0; qf < 2; ++qf) {
    const int qrow = qb * 128 + wid * 32 + qf * 16 + l15;
    const float inv = 1.f / l2[qf];
    const size_t rowbase = ((size_t)(b * SEQ + qrow)) * N_EMBD + h * HEAD_DIM;
#pragma unroll
    for (int u = 0; u < 4; ++u) {
      uint2 pk;
      pk.x = packbf2(o[qf][u][0] * inv, o[qf][u][1] * inv);
      pk.y = packbf2(o[qf][u][2] * inv, o[qf][u][3] * inv);
      *(uint2*)&ctx[rowbase + u * 16 + quad * 4] = pk;
    }
  }
}

// ---------- launch ----------

extern "C" void kernel_launch(void* const* d_in, const int* in_sizes, int n_in,
                              void* d_out, int out_size, void* d_ws, size_t ws_size,
                              hipStream_t stream) {
  const float* x      = (const float*)d_in[0];
  const float* w_attn = (const float*)d_in[1];
  const float* b_attn = (const float*)d_in[2];
  const float* w_proj = (const float*)d_in[3];
  const float* b_proj = (const float*)d_in[4];
  float* out = (float*)d_out;

  char* ws = (char*)d_ws;
  u16* xb  = (u16*)(ws);                        // 8 MB (reused as ctx)
  u16* waT = (u16*)(ws + ((size_t)8 << 20));    // 6 MB
  u16* wpT = (u16*)(ws + ((size_t)14 << 20));   // 2 MB
  u16* qb  = (u16*)(ws + ((size_t)16 << 20));   // 8 MB
  u16* kb  = (u16*)(ws + ((size_t)24 << 20));   // 8 MB
  u16* vtb = (u16*)(ws + ((size_t)32 << 20));   // 8 MB
  u16* po  = (u16*)(ws + ((size_t)40 << 20));   // 16 MB partial O
  float2* ml = (float2*)(ws + ((size_t)56 << 20)); // 1 MB (m,l)  total 57 MB
  u16* ctx = xb;  // x (bf16) is dead after GEMM1

  prep_kernel<<<dim3(3072), 256, 0, stream>>>(x, xb, w_attn, waT, w_proj, wpT);
  gemm_bt<1, 128><<<dim3((3 * N_EMBD) / 128, M_TOT / 128), 256, 0, stream>>>(
      xb, waT, b_attn, nullptr, qb, kb, vtb, M_TOT, 3 * N_EMBD, N_EMBD);
  if (ws_size >= ((size_t)57 << 20)) {
    attn_split<<<dim3(32, BATCH * N_HEAD), 256, 0, stream>>>(qb, kb, vtb, po, ml);
    attn_merge<<<dim3(16, BATCH * N_HEAD), 256, 0, stream>>>(po, ml, ctx);
  } else {
    attn_fused<<<dim3(SEQ / 128, BATCH * N_HEAD), 256, 0, stream>>>(qb, kb, vtb, ctx);
  }
  gemm_bt<0, 64><<<dim3(N_EMBD / 64, M_TOT / 128), 256, 0, stream>>>(
      ctx, wpT, b_proj, out, nullptr, nullptr, nullptr, M_TOT, N_EMBD, N_EMBD);
}

// Round 9
// 195.635 us; speedup vs baseline: 1.0016x; 1.0016x over previous
//
#include <hip/hip_runtime.h>
#include <hip/hip_bf16.h>
#include <cstdint>
#include <cstddef>

typedef unsigned short u16;
typedef unsigned int u32;
using bf16x8 = __attribute__((ext_vector_type(8))) __bf16;
using f32x4  = __attribute__((ext_vector_type(4))) float;

#define N_EMBD 1024
#define N_HEAD 16
#define HEAD_DIM 64
#define BATCH 2
#define SEQ 2048
#define M_TOT (BATCH * SEQ)  // 4096
#define NEG_BIG (-3.0e38f)

// ---------- helpers ----------

__device__ __forceinline__ u16 f2bf(float f) {
  union { float f; u32 u; } v;
  v.f = f;
  u32 u = v.u;
  u32 r = (u + 0x7FFFu + ((u >> 16) & 1u)) >> 16;  // RNE
  return (u16)r;
}

__device__ __forceinline__ float bf2f(u16 h) {
  union { u32 u; float f; } v;
  v.u = ((u32)h) << 16;
  return v.f;
}

__device__ __forceinline__ u32 packbf2(float a, float b) {
  union { __hip_bfloat162 h; u32 u; } cv;
  cv.h = __float22bfloat162_rn(float2{a, b});
  return cv.u;
}

// async global->LDS, 16B per lane; dst is wave-uniform base (HW adds lane*16)
__device__ __forceinline__ void g2l16(const void* g, void* l) {
  __builtin_amdgcn_global_load_lds((__attribute__((address_space(1))) void*)(g),
                                   (__attribute__((address_space(3))) void*)(l),
                                   16, 0, 0);
}

// Pipelined barriers: wait only the oldest in-flight loads, keep the newest
// N (next tile's prefetch) in flight across the barrier.
__device__ __forceinline__ void pipe_barrier4() {
  asm volatile("s_waitcnt vmcnt(4)\n\ts_barrier" ::: "memory");
}
__device__ __forceinline__ void pipe_barrier3() {
  asm volatile("s_waitcnt vmcnt(3)\n\ts_barrier" ::: "memory");
}
__device__ __forceinline__ void pipe_barrier0() {
  asm volatile("s_waitcnt vmcnt(0)\n\ts_barrier" ::: "memory");
}
__device__ __forceinline__ void ds_barrier() {
  asm volatile("s_waitcnt lgkmcnt(0)\n\ts_barrier" ::: "memory");
}

// ---------- fused prep: x fp32->bf16 + both weight transposes ----------
// blocks [0,2048): conv; [2048,2816): w_attn^T (48x16); [2816,3072): w_proj^T.

__global__ __launch_bounds__(256) void prep_kernel(const float* __restrict__ x,
                                                   u16* __restrict__ xb,
                                                   const float* __restrict__ wa,
                                                   u16* __restrict__ waT,
                                                   const float* __restrict__ wp,
                                                   u16* __restrict__ wpT) {
  __shared__ float tile[64][65];
  const int bid = blockIdx.x;
  const int tid = threadIdx.x;
  if (bid < 2048) {
    int i = (bid * 256 + tid) * 8;
    float4 a = *(const float4*)(x + i);
    float4 b = *(const float4*)(x + i + 4);
    union { u16 s[8]; uint4 v; } o;
    o.s[0] = f2bf(a.x); o.s[1] = f2bf(a.y); o.s[2] = f2bf(a.z); o.s[3] = f2bf(a.w);
    o.s[4] = f2bf(b.x); o.s[5] = f2bf(b.y); o.s[6] = f2bf(b.z); o.s[7] = f2bf(b.w);
    *(uint4*)(xb + i) = o.v;
    return;
  }
  const float* src; u16* dst; int R, C, c0, r0;
  if (bid < 2048 + 768) {
    int t = bid - 2048;
    src = wa; dst = waT; R = N_EMBD; C = 3 * N_EMBD;
    c0 = (t % 48) * 64; r0 = (t / 48) * 64;
  } else {
    int t = bid - 2816;
    src = wp; dst = wpT; R = N_EMBD; C = N_EMBD;
    c0 = (t % 16) * 64; r0 = (t / 16) * 64;
  }
#pragma unroll
  for (int i = 0; i < 16; ++i) {
    int idx = tid + i * 256;
    int r = idx >> 6, c = idx & 63;
    tile[r][c] = src[(size_t)(r0 + r) * C + (c0 + c)];
  }
  __syncthreads();
#pragma unroll
  for (int i = 0; i < 16; ++i) {
    int idx = tid + i * 256;
    int cc = idx >> 6, rr = idx & 63;
    dst[(size_t)(c0 + cc) * R + (r0 + rr)] = f2bf(tile[rr][cc]);
  }
}

// ---------- GEMM: C[M,TN-tiles] = A[M,K] * Bt[N,K]^T + bias ----------
// NBUF=3, prefetch distance 2, one raw s_barrier/iter, vmcnt keeps the next
// tile's loads in flight. TN = 128 (4 waves 2x2 of 64x64) or 64 (4 waves of
// 32x64 -> 512 blocks for GEMM2's small N).
// MODE 0: fp32 out row-major [M,N]
// MODE 1: qkv epilogue -> q[B,H,S,D], k[B,H,S,D], v^T[B,H,D,S], all bf16

template <int MODE, int TN>
__global__ __launch_bounds__(256) void gemm_bt(const u16* __restrict__ A,
                                               const u16* __restrict__ Bt,
                                               const float* __restrict__ bias,
                                               float* __restrict__ outF,
                                               u16* __restrict__ qb, u16* __restrict__ kb,
                                               u16* __restrict__ vtb, int M, int N, int K) {
  constexpr int MI = (TN == 128) ? 4 : 2;   // m-frags per wave
  __shared__ u16 As[3][128 * 32];
  __shared__ u16 Bs[3][TN * 32];
  const int tid = threadIdx.x;
  const int wid = tid >> 6;
  const int lane = tid & 63;
  const int quad = lane >> 4;
  const int l15 = lane & 15;
  const int m0 = blockIdx.y * 128;
  const int n0 = blockIdx.x * TN;
  const int wm = (TN == 128) ? (wid >> 1) : wid;
  const int wn = (TN == 128) ? (wid & 1) : 0;

  f32x4 acc[MI][4];
#pragma unroll
  for (int i = 0; i < MI; ++i)
#pragma unroll
    for (int j = 0; j < 4; ++j) acc[i][j] = (f32x4){0.f, 0.f, 0.f, 0.f};

  const int lrow = lane >> 2;          // 0..15
  const int lchunk = (lane & 3) * 8;   // element offset within 32-col row

  auto stage = [&](int t, int b) {
#pragma unroll
    for (int i = 0; i < 2; ++i) {
      int li = wid * 2 + i;
      g2l16(A + (size_t)(m0 + li * 16 + lrow) * K + t * 32 + lchunk, &As[b][li * 512]);
    }
    if (TN == 128) {
#pragma unroll
      for (int i = 0; i < 2; ++i) {
        int li = wid * 2 + i;
        g2l16(Bt + (size_t)(n0 + li * 16 + lrow) * K + t * 32 + lchunk, &Bs[b][li * 512]);
      }
    } else {
      g2l16(Bt + (size_t)(n0 + wid * 16 + lrow) * K + t * 32 + lchunk, &Bs[b][wid * 512]);
    }
  };

  const int niter = K >> 5;
  stage(0, 0);
  stage(1, 1);

  int buf = 0;
  for (int it = 0; it < niter; ++it) {
    if (it < niter - 1) {
      if (TN == 128) pipe_barrier4(); else pipe_barrier3();
    } else {
      pipe_barrier0();
    }
    if (it + 2 < niter) {
      int b2 = buf + 2; if (b2 >= 3) b2 -= 3;
      stage(it + 2, b2);
    }
    bf16x8 af[MI], bfv[4];
#pragma unroll
    for (int i = 0; i < MI; ++i)
      af[i] = *(const bf16x8*)&As[buf][(wm * (MI * 16) + i * 16 + l15) * 32 + quad * 8];
#pragma unroll
    for (int j = 0; j < 4; ++j)
      bfv[j] = *(const bf16x8*)&Bs[buf][(wn * 64 + j * 16 + l15) * 32 + quad * 8];
#pragma unroll
    for (int i = 0; i < MI; ++i)
#pragma unroll
      for (int j = 0; j < 4; ++j)
        acc[i][j] = __builtin_amdgcn_mfma_f32_16x16x32_bf16(af[i], bfv[j], acc[i][j], 0, 0, 0);
    buf = (buf + 1 == 3) ? 0 : buf + 1;
  }

  float bj[4];
#pragma unroll
  for (int j = 0; j < 4; ++j) bj[j] = bias[n0 + wn * 64 + j * 16 + l15];

  if (MODE == 1 && (n0 >> 10) == 2) {
    // v slab: pack 4 consecutive s into one 8B store; vtb[bh][d][s]
#pragma unroll
    for (int i = 0; i < MI; ++i) {
#pragma unroll
      for (int j = 0; j < 4; ++j) {
        int col = n0 + wn * 64 + j * 16 + l15;
        int e = col & 1023;
        int h = e >> 6, d = e & 63;
        int mg0 = m0 + wm * (MI * 16) + i * 16 + quad * 4;
        int b = mg0 >> 11, s0 = mg0 & 2047;
        int bh = b * N_HEAD + h;
        uint2 pk;
        pk.x = packbf2(acc[i][j][0] + bj[j], acc[i][j][1] + bj[j]);
        pk.y = packbf2(acc[i][j][2] + bj[j], acc[i][j][3] + bj[j]);
        *(uint2*)&vtb[((size_t)bh * HEAD_DIM + d) * SEQ + s0] = pk;
      }
    }
    return;
  }

#pragma unroll
  for (int i = 0; i < MI; ++i) {
#pragma unroll
    for (int j = 0; j < 4; ++j) {
      int col = n0 + wn * 64 + j * 16 + l15;
#pragma unroll
      for (int r = 0; r < 4; ++r) {
        int m_g = m0 + wm * (MI * 16) + i * 16 + quad * 4 + r;
        float v = acc[i][j][r] + bj[j];
        if (MODE == 0) {
          outF[(size_t)m_g * N + col] = v;
        } else {
          int which = col >> 10;      // 0=q 1=k (v handled above)
          int e = col & 1023;
          int h = e >> 6, d = e & 63;
          int b = m_g >> 11, s = m_g & 2047;
          int bh = b * N_HEAD + h;
          u16 bv = f2bf(v);
          if (which == 0)
            qb[((size_t)bh * SEQ + s) * HEAD_DIM + d] = bv;
          else
            kb[((size_t)bh * SEQ + s) * HEAD_DIM + d] = bv;
        }
      }
    }
  }
}

// ---------- split-K flash attention (causal), NPART-way ----------
// Q-block 128 (wave owns 32 q rows = 2 frags). Key range of q-tile qb
// (nt = 2qb+2 tiles of 64 keys) split into NPART parts of ceil/floor(nt/NPART)
// tiles; grid (16*NPART, 32 bh). The round-8 lesson: the kernel is bound by
// the LONGEST block's serial tile chain (~5k cyc/tile), not aggregate
// throughput — NPART=4 halves the critical path vs NPART=2 (8 vs 16 tiles).
// Empty parts write (m=NEG_BIG, l=0, O=0); merge weights them to zero.
// K NBUF=2, V NBUF=2; V frags read to regs BEFORE the ds_barrier so
// stage(j+2) can reuse both buffers right after it. Ps stride 64 with
// 16B-chunk XOR swizzle. LDS 40960 B. One vm-barrier (vmcnt(4)) + one
// ds-barrier per iter.

template <int NPART>
__global__ __launch_bounds__(256, 3) void attn_split(const u16* __restrict__ q,
                                                     const u16* __restrict__ k,
                                                     const u16* __restrict__ vt,
                                                     u16* __restrict__ po,
                                                     float2* __restrict__ ml) {
  __shared__ u16 Ks[2][64 * 64];
  __shared__ u16 Vs[2][64 * 64];   // [d][key]
  __shared__ u16 Ps[4][16 * 64];   // per-wave P [q][key], 16B-chunk XOR swizzle

  const int tid = threadIdx.x;
  const int wid = tid >> 6;
  const int lane = tid & 63;
  const int quad = lane >> 4;
  const int l15 = lane & 15;
  const int l7 = l15 & 7;
  const int raw = blockIdx.x;
  const int part = raw & (NPART - 1);
  const int cc = raw / NPART;
  const int yy = blockIdx.y;
  const int g = (cc + yy) & 7;
  const int hi = ((cc >> 3) ^ (yy >> 3)) & 1;
  const int qb = hi ? (15 - g) : g;
  const size_t base = (size_t)yy * SEQ * HEAD_DIM;
  const int lrow8 = lane >> 3;                 // 0..7
  const int swz8 = ((lane & 7) ^ lrow8) * 8;   // swizzled source chunk
  const int nt = 2 * qb + 2;
  const int t0 = (nt * part) / NPART;          // first global tile index
  const int ni = (nt * (part + 1)) / NPART - t0;  // tiles in this part
  const int p = (yy * 16 + qb) * NPART + part; // partial slot

  // Q B-frags, direct to regs (4 b128 global loads; oldest in vmcnt order)
  bf16x8 bq[2][2];
#pragma unroll
  for (int qf = 0; qf < 2; ++qf)
#pragma unroll
    for (int kk = 0; kk < 2; ++kk)
      bq[qf][kk] = *(const bf16x8*)(q + base +
          (size_t)(qb * 128 + wid * 32 + qf * 16 + l15) * HEAD_DIM + kk * 32 + quad * 8);

  auto stageK = [&](int j, int b) {
#pragma unroll
    for (int i = 0; i < 2; ++i) {
      int li = wid * 2 + i;
      g2l16(k + base + (size_t)(j * 64 + li * 8 + lrow8) * HEAD_DIM + swz8, &Ks[b][li * 512]);
    }
  };
  auto stageV = [&](int j, int b) {
#pragma unroll
    for (int i = 0; i < 2; ++i) {
      int li = wid * 2 + i;
      g2l16(vt + base + (size_t)(li * 8 + lrow8) * SEQ + j * 64 + swz8, &Vs[b][li * 512]);
    }
  };

  if (ni >= 1) { stageK(t0, 0); stageV(t0, 0); }
  if (ni >= 2) { stageK(t0 + 1, 1); stageV(t0 + 1, 1); }

  float m2[2] = {NEG_BIG, NEG_BIG}, l2[2] = {0.f, 0.f};
  f32x4 o[2][4];
#pragma unroll
  for (int qf = 0; qf < 2; ++qf)
#pragma unroll
    for (int u = 0; u < 4; ++u) o[qf][u] = (f32x4){0.f, 0.f, 0.f, 0.f};

  const float c2 = 0.125f * 1.44269504f;  // (1/sqrt(64)) * log2(e)
  const int mask_from = 2 * qb;

  for (int i = 0; i < ni; ++i) {
    const int jj = t0 + i;
    const int buf = i & 1;
    // outstanding here: tile jj+1's K+V (4 loads) -> vmcnt(4) proves jj landed
    if (i < ni - 1) pipe_barrier4(); else pipe_barrier0();

    // V frags to regs first (used only after softmax; read must precede the
    // ds_barrier because stage(jj+2) reuses this buffer)
    bf16x8 vv[4][2];
#pragma unroll
    for (int u = 0; u < 4; ++u)
#pragma unroll
      for (int kk = 0; kk < 2; ++kk)
        vv[u][kk] = *(const bf16x8*)&Vs[buf][(u * 16 + l15) * 64 + (((kk * 4 + quad) ^ l7) * 8)];

    // S^T = K · Q^T : K frag read once, feeds both q-frags
    f32x4 st[2][4];
#pragma unroll
    for (int qf = 0; qf < 2; ++qf)
#pragma unroll
      for (int t = 0; t < 4; ++t) st[qf][t] = (f32x4){0.f, 0.f, 0.f, 0.f};
#pragma unroll
    for (int kk = 0; kk < 2; ++kk)
#pragma unroll
      for (int t = 0; t < 4; ++t) {
        bf16x8 ka = *(const bf16x8*)&Ks[buf][(t * 16 + l15) * 64 + (((kk * 4 + quad) ^ l7) * 8)];
        st[0][t] = __builtin_amdgcn_mfma_f32_16x16x32_bf16(ka, bq[0][kk], st[0][t], 0, 0, 0);
        st[1][t] = __builtin_amdgcn_mfma_f32_16x16x32_bf16(ka, bq[1][kk], st[1][t], 0, 0, 0);
      }

    // all waves' K/V reads of this buffer retired -> reusable
    ds_barrier();
    if (i + 2 < ni) { stageK(jj + 2, buf); stageV(jj + 2, buf); }

    // causal mask (global tile index vs q rows)
    if (jj >= mask_from) {
#pragma unroll
      for (int qf = 0; qf < 2; ++qf) {
        int qrow = qb * 128 + wid * 32 + qf * 16 + l15;
#pragma unroll
        for (int t = 0; t < 4; ++t)
#pragma unroll
          for (int r = 0; r < 4; ++r) {
            int key = jj * 64 + t * 16 + quad * 4 + r;
            if (key > qrow) st[qf][t][r] = -INFINITY;
          }
      }
    }

    // online softmax (log2 domain), per q-frag; raw v_exp_f32
#pragma unroll
    for (int qf = 0; qf < 2; ++qf) {
      float mx = -INFINITY;
#pragma unroll
      for (int t = 0; t < 4; ++t)
#pragma unroll
        for (int r = 0; r < 4; ++r) mx = fmaxf(mx, st[qf][t][r]);
      mx = fmaxf(mx, __shfl_xor(mx, 16));
      mx = fmaxf(mx, __shfl_xor(mx, 32));
      float m2new = fmaxf(m2[qf], mx * c2);
      float s = 0.f;
#pragma unroll
      for (int t = 0; t < 4; ++t)
#pragma unroll
        for (int r = 0; r < 4; ++r) {
          float pv = __builtin_amdgcn_exp2f(__builtin_fmaf(st[qf][t][r], c2, -m2new));
          st[qf][t][r] = pv;
          s += pv;
        }
      s += __shfl_xor(s, 16);
      s += __shfl_xor(s, 32);
      if (__any(m2new > m2[qf])) {
        float al = __builtin_amdgcn_exp2f(m2[qf] - m2new);
        l2[qf] = l2[qf] * al + s;
#pragma unroll
        for (int u = 0; u < 4; ++u)
#pragma unroll
          for (int r = 0; r < 4; ++r) o[qf][u][r] *= al;
      } else {
        l2[qf] += s;
      }
      m2[qf] = m2new;
    }

    // per q-frag: P staging (wave-private, swizzled) then O^T += V^T · P^T
#pragma unroll
    for (int qf = 0; qf < 2; ++qf) {
#pragma unroll
      for (int t = 0; t < 4; ++t) {
        uint2 pk;
        pk.x = packbf2(st[qf][t][0], st[qf][t][1]);
        pk.y = packbf2(st[qf][t][2], st[qf][t][3]);
        // logical 16B chunk c16 = 2t + (quad>>1), low half sel = quad&1
        *(uint2*)&Ps[wid][l15 * 64 + (((2 * t + (quad >> 1)) ^ l7) * 8) + (quad & 1) * 4] = pk;
      }
#pragma unroll
      for (int kk = 0; kk < 2; ++kk) {
        // logical 16B chunk c16 = 4kk + quad
        bf16x8 bp = *(const bf16x8*)&Ps[wid][l15 * 64 + (((4 * kk + quad) ^ l7) * 8)];
#pragma unroll
        for (int u = 0; u < 4; ++u)
          o[qf][u] = __builtin_amdgcn_mfma_f32_16x16x32_bf16(vv[u][kk], bp, o[qf][u], 0, 0, 0);
      }
    }
  }

  // epilogue: unnormalized O^T partial (bf16) + (m,l) per q row
#pragma unroll
  for (int qf = 0; qf < 2; ++qf) {
    const int qloc = wid * 32 + qf * 16 + l15;
    u16* pr = po + (size_t)p * (128 * 64) + (size_t)qloc * 64;
#pragma unroll
    for (int u = 0; u < 4; ++u) {
      uint2 pk;
      pk.x = packbf2(o[qf][u][0], o[qf][u][1]);
      pk.y = packbf2(o[qf][u][2], o[qf][u][3]);
      *(uint2*)&pr[u * 16 + quad * 4] = pk;
    }
    if (quad == 0) ml[(size_t)p * 128 + qloc] = float2{m2[qf], l2[qf]};
  }
}

// ---------- merge NPART split-K partials -> ctx ----------
// grid (16 qb, 32 bh) x 256 thr; thread owns q = tid>>1, d = (tid&1)*32..+31.

template <int NPART>
__global__ __launch_bounds__(256) void attn_merge(const u16* __restrict__ po,
                                                  const float2* __restrict__ ml,
                                                  u16* __restrict__ ctx) {
  const int qb = blockIdx.x, yy = blockIdx.y;
  const int tid = threadIdx.x;
  const int qloc = tid >> 1;
  const int d0 = (tid & 1) * 32;
  const int p0 = (yy * 16 + qb) * NPART;
  float2 mlv[NPART];
  float m = -INFINITY;
#pragma unroll
  for (int r = 0; r < NPART; ++r) {
    mlv[r] = ml[(size_t)(p0 + r) * 128 + qloc];
    m = fmaxf(m, mlv[r].x);
  }
  float li = 0.f, sc[NPART];
#pragma unroll
  for (int r = 0; r < NPART; ++r) {
    sc[r] = __builtin_amdgcn_exp2f(mlv[r].x - m);
    li += mlv[r].y * sc[r];
  }
  const float inv = 1.f / li;
#pragma unroll
  for (int r = 0; r < NPART; ++r) sc[r] *= inv;
  const int bb = yy >> 4, h = yy & 15;
  const u16* pbase = po + (size_t)p0 * (128 * 64) + (size_t)qloc * 64 + d0;
  u16* outp = ctx + ((size_t)(bb * SEQ + qb * 128 + qloc)) * N_EMBD + h * HEAD_DIM + d0;
#pragma unroll
  for (int c = 0; c < 4; ++c) {
    float acc[8];
#pragma unroll
    for (int e = 0; e < 8; ++e) acc[e] = 0.f;
#pragma unroll
    for (int r = 0; r < NPART; ++r) {
      union { uint4 v; u16 s[8]; } ua;
      ua.v = *(const uint4*)(pbase + (size_t)r * (128 * 64) + c * 8);
#pragma unroll
      for (int e = 0; e < 8; ++e) acc[e] = __builtin_fmaf(bf2f(ua.s[e]), sc[r], acc[e]);
    }
    union { uint4 v; u32 w[4]; } uo;
#pragma unroll
    for (int e = 0; e < 8; e += 2) uo.w[e >> 1] = packbf2(acc[e], acc[e + 1]);
    *(uint4*)(outp + c * 8) = uo.v;
  }
}

// ---------- fused fallback attention (round-5 structure) ----------

__global__ __launch_bounds__(256, 3) void attn_fused(const u16* __restrict__ q,
                                                     const u16* __restrict__ k,
                                                     const u16* __restrict__ vt,
                                                     u16* __restrict__ ctx) {
  __shared__ u16 Ks[2][64 * 64];
  __shared__ u16 Vs[2][64 * 64];
  __shared__ u16 Ps[4][16 * 72];
  const int tid = threadIdx.x;
  const int wid = tid >> 6;
  const int lane = tid & 63;
  const int quad = lane >> 4;
  const int l15 = lane & 15;
  const int l7 = l15 & 7;
  const int yy = blockIdx.y;
  const int cc = (blockIdx.x + yy) & 15;
  const int qb = (yy < 16) ? cc : 15 - cc;
  const size_t base = (size_t)yy * SEQ * HEAD_DIM;
  const int lrow8 = lane >> 3;
  const int swz8 = ((lane & 7) ^ lrow8) * 8;
  const int nt = 2 * qb + 2;

  bf16x8 bq[2][2];
#pragma unroll
  for (int qf = 0; qf < 2; ++qf)
#pragma unroll
    for (int kk = 0; kk < 2; ++kk)
      bq[qf][kk] = *(const bf16x8*)(q + base +
          (size_t)(qb * 128 + wid * 32 + qf * 16 + l15) * HEAD_DIM + kk * 32 + quad * 8);

  auto stage = [&](int j, int b) {
#pragma unroll
    for (int i = 0; i < 2; ++i) {
      int li = wid * 2 + i;
      int r = li * 8 + lrow8;
      g2l16(k + base + (size_t)(j * 64 + r) * HEAD_DIM + swz8, &Ks[b][li * 512]);
      g2l16(vt + base + (size_t)r * SEQ + j * 64 + swz8, &Vs[b][li * 512]);
    }
  };
  stage(0, 0);
  stage(1, 1);

  float m2[2] = {NEG_BIG, NEG_BIG}, l2[2] = {0.f, 0.f};
  f32x4 o[2][4];
#pragma unroll
  for (int qf = 0; qf < 2; ++qf)
#pragma unroll
    for (int u = 0; u < 4; ++u) o[qf][u] = (f32x4){0.f, 0.f, 0.f, 0.f};
  const float c2 = 0.125f * 1.44269504f;

  int buf = 0;
  for (int j = 0; j < nt; ++j) {
    if (j < nt - 1) pipe_barrier4(); else pipe_barrier0();
    bf16x8 vv[4][2];
#pragma unroll
    for (int u = 0; u < 4; ++u)
#pragma unroll
      for (int kk = 0; kk < 2; ++kk)
        vv[u][kk] = *(const bf16x8*)&Vs[buf][(u * 16 + l15) * 64 + (((kk * 4 + quad) ^ l7) * 8)];
    f32x4 st[2][4];
#pragma unroll
    for (int qf = 0; qf < 2; ++qf)
#pragma unroll
      for (int t = 0; t < 4; ++t) st[qf][t] = (f32x4){0.f, 0.f, 0.f, 0.f};
#pragma unroll
    for (int kk = 0; kk < 2; ++kk)
#pragma unroll
      for (int t = 0; t < 4; ++t) {
        bf16x8 ka = *(const bf16x8*)&Ks[buf][(t * 16 + l15) * 64 + (((kk * 4 + quad) ^ l7) * 8)];
        st[0][t] = __builtin_amdgcn_mfma_f32_16x16x32_bf16(ka, bq[0][kk], st[0][t], 0, 0, 0);
        st[1][t] = __builtin_amdgcn_mfma_f32_16x16x32_bf16(ka, bq[1][kk], st[1][t], 0, 0, 0);
      }
    ds_barrier();
    if (j + 2 < nt) stage(j + 2, buf);
    if (j >= 2 * qb) {
#pragma unroll
      for (int qf = 0; qf < 2; ++qf) {
        int qrow = qb * 128 + wid * 32 + qf * 16 + l15;
#pragma unroll
        for (int t = 0; t < 4; ++t)
#pragma unroll
          for (int r = 0; r < 4; ++r) {
            int key = j * 64 + t * 16 + quad * 4 + r;
            if (key > qrow) st[qf][t][r] = -INFINITY;
          }
      }
    }
#pragma unroll
    for (int qf = 0; qf < 2; ++qf) {
      float mx = -INFINITY;
#pragma unroll
      for (int t = 0; t < 4; ++t)
#pragma unroll
        for (int r = 0; r < 4; ++r) mx = fmaxf(mx, st[qf][t][r]);
      mx = fmaxf(mx, __shfl_xor(mx, 16));
      mx = fmaxf(mx, __shfl_xor(mx, 32));
      float m2new = fmaxf(m2[qf], mx * c2);
      float s = 0.f;
#pragma unroll
      for (int t = 0; t < 4; ++t)
#pragma unroll
        for (int r = 0; r < 4; ++r) {
          float pv = __builtin_amdgcn_exp2f(__builtin_fmaf(st[qf][t][r], c2, -m2new));
          st[qf][t][r] = pv;
          s += pv;
        }
      s += __shfl_xor(s, 16);
      s += __shfl_xor(s, 32);
      if (__any(m2new > m2[qf])) {
        float al = __builtin_amdgcn_exp2f(m2[qf] - m2new);
        l2[qf] = l2[qf] * al + s;
#pragma unroll
        for (int u = 0; u < 4; ++u)
#pragma unroll
          for (int r = 0; r < 4; ++r) o[qf][u][r] *= al;
      } else {
        l2[qf] += s;
      }
      m2[qf] = m2new;
    }
#pragma unroll
    for (int qf = 0; qf < 2; ++qf) {
#pragma unroll
      for (int t = 0; t < 4; ++t) {
        uint2 pk;
        pk.x = packbf2(st[qf][t][0], st[qf][t][1]);
        pk.y = packbf2(st[qf][t][2], st[qf][t][3]);
        *(uint2*)&Ps[wid][l15 * 72 + t * 16 + quad * 4] = pk;
      }
#pragma unroll
      for (int kk = 0; kk < 2; ++kk) {
        bf16x8 bp = *(const bf16x8*)&Ps[wid][l15 * 72 + kk * 32 + quad * 8];
#pragma unroll
        for (int u = 0; u < 4; ++u)
          o[qf][u] = __builtin_amdgcn_mfma_f32_16x16x32_bf16(vv[u][kk], bp, o[qf][u], 0, 0, 0);
      }
    }
    buf ^= 1;
  }
  const int b = yy >> 4, h = yy & 15;
#pragma unroll
  for (int qf = 0; qf < 2; ++qf) {
    const int qrow = qb * 128 + wid * 32 + qf * 16 + l15;
    const float inv = 1.f / l2[qf];
    const size_t rowbase = ((size_t)(b * SEQ + qrow)) * N_EMBD + h * HEAD_DIM;
#pragma unroll
    for (int u = 0; u < 4; ++u) {
      uint2 pk;
      pk.x = packbf2(o[qf][u][0] * inv, o[qf][u][1] * inv);
      pk.y = packbf2(o[qf][u][2] * inv, o[qf][u][3] * inv);
      *(uint2*)&ctx[rowbase + u * 16 + quad * 4] = pk;
    }
  }
}

// ---------- launch ----------

extern "C" void kernel_launch(void* const* d_in, const int* in_sizes, int n_in,
                              void* d_out, int out_size, void* d_ws, size_t ws_size,
                              hipStream_t stream) {
  const float* x      = (const float*)d_in[0];
  const float* w_attn = (const float*)d_in[1];
  const float* b_attn = (const float*)d_in[2];
  const float* w_proj = (const float*)d_in[3];
  const float* b_proj = (const float*)d_in[4];
  float* out = (float*)d_out;

  char* ws = (char*)d_ws;
  u16* xb  = (u16*)(ws);                        // 8 MB (reused as ctx)
  u16* waT = (u16*)(ws + ((size_t)8 << 20));    // 6 MB
  u16* wpT = (u16*)(ws + ((size_t)14 << 20));   // 2 MB
  u16* qb  = (u16*)(ws + ((size_t)16 << 20));   // 8 MB
  u16* kb  = (u16*)(ws + ((size_t)24 << 20));   // 8 MB
  u16* vtb = (u16*)(ws + ((size_t)32 << 20));   // 8 MB
  u16* po  = (u16*)(ws + ((size_t)40 << 20));   // 16/32 MB partial O
  float2* ml2 = (float2*)(ws + ((size_t)56 << 20)); // 1 MB (2-way)
  float2* ml4 = (float2*)(ws + ((size_t)72 << 20)); // 2 MB (4-way) total 74 MB
  u16* ctx = xb;  // x (bf16) is dead after GEMM1

  prep_kernel<<<dim3(3072), 256, 0, stream>>>(x, xb, w_attn, waT, w_proj, wpT);
  gemm_bt<1, 128><<<dim3((3 * N_EMBD) / 128, M_TOT / 128), 256, 0, stream>>>(
      xb, waT, b_attn, nullptr, qb, kb, vtb, M_TOT, 3 * N_EMBD, N_EMBD);
  if (ws_size >= ((size_t)74 << 20)) {
    attn_split<4><<<dim3(64, BATCH * N_HEAD), 256, 0, stream>>>(qb, kb, vtb, po, ml4);
    attn_merge<4><<<dim3(16, BATCH * N_HEAD), 256, 0, stream>>>(po, ml4, ctx);
  } else if (ws_size >= ((size_t)57 << 20)) {
    attn_split<2><<<dim3(32, BATCH * N_HEAD), 256, 0, stream>>>(qb, kb, vtb, po, ml2);
    attn_merge<2><<<dim3(16, BATCH * N_HEAD), 256, 0, stream>>>(po, ml2, ctx);
  } else {
    attn_fused<<<dim3(SEQ / 128, BATCH * N_HEAD), 256, 0, stream>>>(qb, kb, vtb, ctx);
  }
  gemm_bt<0, 64><<<dim3(N_EMBD / 64, M_TOT / 128), 256, 0, stream>>>(
      ctx, wpT, b_proj, out, nullptr, nullptr, nullptr, M_TOT, N_EMBD, N_EMBD);
}